// Round 2
// baseline (22.735 us; speedup 1.0000x reference)
//
#include <hip/hip_runtime.h>

// RBF activation: out[b,h,w,c] = sum_j w[c,j] * exp(-0.5*((x-mu_j)/sigma)^2)
// mu_j = linspace(-0.25, 0.25, 31), sigma = 0.5/30 = 1/60.
//
// Factorized form: s = (x-vmin)/sigma, j0 = clamp(round(s),0,30), t = s-j0.
// exp(-0.5 (s-j)^2) = exp(-t^2/2 + t k) * exp(-k^2/2) for j = j0+k.
// Truncate |k|<=5 (omitted terms < 1e-8 abs). Horner over k'=k+5 in r=e^t,
// with G5 = exp(-t^2/2 - 5t) folded into a single exp2.

#define NK 31
#define NC 64
#define GUARD 5
#define ROWS (NK + 2 * GUARD)  // 41: rows [5,35] hold w^T, guards are 0

__global__ __launch_bounds__(256) void rbf_kernel(const float* __restrict__ x,
                                                  const float* __restrict__ w,
                                                  float* __restrict__ out,
                                                  int n) {
    __shared__ float wl[ROWS][NC];  // [j+GUARD][c], zero guard rows

    // Cooperative fill: 41*64 = 2624 entries / 256 threads
    for (int i = threadIdx.x; i < ROWS * NC; i += 256) {
        int row = i >> 6;
        int c = i & 63;
        int j = row - GUARD;
        wl[row][c] = (j >= 0 && j < NK) ? w[c * NK + j] : 0.0f;
    }
    __syncthreads();

    // g[k'] = exp(-(k'-5)^2 / 2)
    const float g0 = 3.7266531720786709e-06f;  // e^-12.5
    const float g1 = 3.3546262790251185e-04f;  // e^-8
    const float g2 = 1.1108996538242306e-02f;  // e^-4.5
    const float g3 = 1.3533528323661270e-01f;  // e^-2
    const float g4 = 6.0653065971263342e-01f;  // e^-0.5
    const float gtab[11] = {g0, g1, g2, g3, g4, 1.0f, g4, g3, g2, g1, g0};

    const float LOG2E = 1.4426950408889634f;

    int stride = gridDim.x * 256;
    for (int i = blockIdx.x * 256 + threadIdx.x; i < n; i += stride) {
        float xv = x[i];
        // s = (x - vmin)/sigma = x*60 + 15
        float s = fmaf(xv, 60.0f, 15.0f);
        float j0f = rintf(s);
        j0f = fminf(fmaxf(j0f, 0.0f), 30.0f);   // v_med3
        float t = s - j0f;
        t = fminf(fmaxf(t, -6.0f), 6.0f);       // tail clamp: keeps r^10 finite
        int j0 = (int)j0f;
        int c = i & 63;
        const float* wp = &wl[j0][c];           // rows j0..j0+10 = j in [j0-5, j0+5]

        float r  = exp2f(t * LOG2E);                                   // e^t
        float G5 = exp2f(t * fmaf(t, -0.72134752044448170f,            // e^(-t^2/2 - 5t)
                                  -7.2134752044448170f));

        // Horner: p = sum_{k'=0..10} (wl[j0+k'][c] * g[k']) * r^k'
        float p = wp[10 * NC] * gtab[10];
        #pragma unroll
        for (int kk = 9; kk >= 0; --kk) {
            p = fmaf(p, r, wp[kk * NC] * gtab[kk]);
        }
        out[i] = p * G5;
    }
}

extern "C" void kernel_launch(void* const* d_in, const int* in_sizes, int n_in,
                              void* d_out, int out_size, void* d_ws, size_t ws_size,
                              hipStream_t stream) {
    const float* x = (const float*)d_in[0];
    const float* w = (const float*)d_in[1];
    float* out = (float*)d_out;
    int n = out_size;  // 8*128*128*64

    int blocks = (n + 255) / 256;
    if (blocks > 2048) blocks = 2048;  // 8 blocks/CU * 256 CU; grid-stride the rest
    rbf_kernel<<<blocks, 256, 0, stream>>>(x, w, out, n);
}